// Round 5
// baseline (2408.789 us; speedup 1.0000x reference)
//
#include <hip/hip_runtime.h>

#define NB 4
#define NN 16384
#define NPT 1024
#define NS 32
#define CIN 64
#define C0 67

__device__ __forceinline__ unsigned long long shfl_xor_u64(unsigned long long v, int m) {
  int lo = __shfl_xor((int)(unsigned)v, m, 64);
  int hi = __shfl_xor((int)(unsigned)(v >> 32), m, 64);
  return ((unsigned long long)(unsigned)hi << 32) | (unsigned)lo;
}

// ---------------- FPS: one block per batch, 256 threads, 64 pts/thread in registers ----
// Round-4 lesson: VGPR_Count=160 -> compiler REMATERIALIZED px/py/pz (re-loaded all
// 192KB from L2 every iteration) instead of keeping them resident. The empty asm
// "+v" pin below makes the loaded values opaque (non-rematerializable), forcing true
// register residency (~300 VGPR < 512 budget at 1 wave/SIMD).
extern "C" __global__ __launch_bounds__(256, 1)
void fps_kernel(const float* __restrict__ xyz, float* __restrict__ newxyz) {
  const int b = blockIdx.x;
  const int tid = threadIdx.x;          // 0..255
  const int wv = tid >> 6, lane = tid & 63;
  const float* base = xyz + (size_t)b * (NN * 3);
  float px[64], py[64], pz[64], md[64];
#pragma unroll
  for (int k = 0; k < 64; ++k) {
    int j = (k << 8) + tid;
    px[k] = base[3 * j + 0];
    py[k] = base[3 * j + 1];
    pz[k] = base[3 * j + 2];
    md[k] = 1e10f;
  }
#pragma unroll
  for (int k = 0; k < 64; ++k) {  // pin: forbid remat-by-reload of the coord arrays
    asm volatile("" : "+v"(px[k]), "+v"(py[k]), "+v"(pz[k]));
  }
  __shared__ unsigned long long part[2][4];  // parity-double-buffered wave-winner keys
  float* onew = newxyz + (size_t)b * (NPT * 3);
  // iteration 0: centroid = point 0 (broadcast load)
  float cx = base[0], cy = base[1], cz = base[2];
  if (tid == 0) { onew[0] = cx; onew[1] = cy; onew[2] = cz; }
  for (int it = 1; it < NPT; ++it) {
    const int p = it & 1;
    float bestv = -1.0f; int bestk = 0;
#pragma unroll
    for (int k = 0; k < 64; ++k) {
      // match numpy exactly: no FMA contraction, sum order (dx2+dy2)+dz2
      float dx = __fsub_rn(px[k], cx);
      float dy = __fsub_rn(py[k], cy);
      float dz = __fsub_rn(pz[k], cz);
      float d = __fadd_rn(__fadd_rn(__fmul_rn(dx, dx), __fmul_rn(dy, dy)), __fmul_rn(dz, dz));
      float mn = fminf(md[k], d);
      md[k] = mn;
      bool gt = mn > bestv;            // strict > keeps earliest k (lowest j in-thread)
      bestv = gt ? mn : bestv;
      bestk = gt ? k : bestk;          // bestk only feeds the integer j below (no array read)
    }
    int bestj = (bestk << 8) + tid;
    // d>=0 so float bits are monotonic; ~idx breaks ties toward the SMALLEST index
    unsigned long long key = ((unsigned long long)__float_as_uint(bestv) << 32) | (unsigned)(~bestj);
    unsigned long long red = key;
#pragma unroll
    for (int off = 32; off > 0; off >>= 1) {
      unsigned long long o = shfl_xor_u64(red, off);
      red = (o > red) ? o : red;
    }
    if (lane == 0) part[p][wv] = red;
    __syncthreads();
    // every thread combines the 4 wave winners locally (broadcast LDS reads)
    unsigned long long g0 = part[p][0], g1 = part[p][1], g2 = part[p][2], g3 = part[p][3];
    unsigned long long ga = (g0 > g1) ? g0 : g1;
    unsigned long long gb = (g2 > g3) ? g2 : g3;
    unsigned long long g = (ga > gb) ? ga : gb;
    int j = (int)(~(unsigned)g);
    int js = __builtin_amdgcn_readfirstlane(j);      // uniform -> scalar loads
    const float* pc = base + 3 * js;
    cx = pc[0]; cy = pc[1]; cz = pc[2];              // bit-identical to source coords
    if (tid == 0) { float* o3 = onew + 3 * it; o3[0] = cx; o3[1] = cy; o3[2] = cz; }
    // no second barrier: next iteration writes the OTHER parity's cells
  }
}

// ---------------- Ball query: one wave per centroid, ordered append with early exit ----------------
extern "C" __global__ __launch_bounds__(256)
void ball_kernel(const float* __restrict__ xyz, const float* __restrict__ newxyz,
                 int* __restrict__ ballidx) {
  const int lwv = threadIdx.x >> 6, lane = threadIdx.x & 63;
  const int wid = blockIdx.x * 4 + lwv;  // centroid id, 0..4095
  const int b = wid >> 10;
  const float* base = xyz + (size_t)b * (NN * 3);
  const float* c = newxyz + (size_t)wid * 3;
  float cx = c[0], cy = c[1], cz = c[2];
  float c2 = __fadd_rn(__fadd_rn(__fmul_rn(cx, cx), __fmul_rn(cy, cy)), __fmul_rn(cz, cz));
  __shared__ int list[4][NS];
  int cnt = 0;
  for (int j0 = 0; j0 < NN; j0 += 64) {
    int j = j0 + lane;
    float xx = base[3 * j + 0], xy = base[3 * j + 1], xz = base[3 * j + 2];
    float x2 = __fadd_rn(__fadd_rn(__fmul_rn(xx, xx), __fmul_rn(xy, xy)), __fmul_rn(xz, xz));
    float dt = __fadd_rn(__fadd_rn(__fmul_rn(cx, xx), __fmul_rn(cy, xy)), __fmul_rn(cz, xz));
    float d2 = __fsub_rn(__fadd_rn(c2, x2), __fmul_rn(2.0f, dt));  // (c2+x2) - 2*dot
    bool in = d2 < 0.25f;
    unsigned long long msk = __ballot(in);
    if (in) {
      int pos = cnt + (int)__popcll(msk & ((1ull << lane) - 1ull));
      if (pos < NS) list[lwv][pos] = j;
    }
    cnt += (int)__popcll(msk);
    if (cnt >= NS) break;
  }
  if (lane < NS) {
    int v;
    if (cnt == 0) v = 0;
    else v = (lane < cnt) ? list[lwv][lane] : list[lwv][0];
    ballidx[wid * NS + lane] = v;
  }
}

// ---------------- Gather + MLP(67->64->64->128) + max-pool, one block per (b,m) ----------------
extern "C" __global__ __launch_bounds__(256)
void mlp_kernel(const float* __restrict__ xyz, const float* __restrict__ feats,
                const float* __restrict__ newxyz, const int* __restrict__ ballidx,
                const float* __restrict__ W1, const float* __restrict__ b1,
                const float* __restrict__ W2, const float* __restrict__ b2,
                const float* __restrict__ W3, const float* __restrict__ b3,
                float* __restrict__ outf) {
  const int bm = blockIdx.x;
  const int b = bm >> 10, m = bm & 1023;
  const int tid = threadIdx.x;
  __align__(16) __shared__ float bufA[32 * 68];  // h0 (stride 68), then h2 (stride 64)
  __align__(16) __shared__ float bufB[32 * 64];  // h1, then partial max
  __shared__ int sidx[NS];
  if (tid < NS) sidx[tid] = ballidx[bm * NS + tid];
  const float* cb = newxyz + (size_t)bm * 3;
  float cx = cb[0], cy = cb[1], cz = cb[2];
  __syncthreads();
  // gather: 8 threads per sample
  {
    int s = tid >> 3, q = tid & 7;
    int j = sidx[s];
    float* row = bufA + s * 68;
    const float* fb = feats + (size_t)b * (CIN * NN) + j;
#pragma unroll
    for (int u = 0; u < 8; ++u) {
      int cc = (q << 3) + u;
      row[3 + cc] = fb[(size_t)cc * NN];
    }
    if (q == 0) {
      const float* p = xyz + ((size_t)b * NN + j) * 3;
      row[0] = __fsub_rn(p[0], cx);
      row[1] = __fsub_rn(p[1], cy);
      row[2] = __fsub_rn(p[2], cz);
      row[67] = 0.0f;
    }
  }
  __syncthreads();
  // layer 1: 67->64   (thread = (o, 8-sample group))
  {
    const int o = tid & 63, g = tid >> 6;
    float w[68];
    const float* wr = W1 + o * C0;
#pragma unroll
    for (int c = 0; c < C0; ++c) w[c] = wr[c];
    w[67] = 0.0f;
    float bias = b1[o];
    float acc[8];
#pragma unroll
    for (int k = 0; k < 8; ++k) acc[k] = bias;
#pragma unroll
    for (int c = 0; c < 68; c += 4) {
#pragma unroll
      for (int k = 0; k < 8; ++k) {
        float4 h = *(const float4*)(bufA + (g * 8 + k) * 68 + c);
        acc[k] = fmaf(w[c], h.x, acc[k]);
        acc[k] = fmaf(w[c + 1], h.y, acc[k]);
        acc[k] = fmaf(w[c + 2], h.z, acc[k]);
        acc[k] = fmaf(w[c + 3], h.w, acc[k]);
      }
    }
#pragma unroll
    for (int k = 0; k < 8; ++k) bufB[(g * 8 + k) * 64 + o] = fmaxf(acc[k], 0.0f);
  }
  __syncthreads();
  // layer 2: 64->64, h2 into bufA with stride 64
  {
    const int o = tid & 63, g = tid >> 6;
    float w[64];
    const float* wr = W2 + o * 64;
#pragma unroll
    for (int c = 0; c < 64; ++c) w[c] = wr[c];
    float bias = b2[o];
    float acc[8];
#pragma unroll
    for (int k = 0; k < 8; ++k) acc[k] = bias;
#pragma unroll
    for (int c = 0; c < 64; c += 4) {
#pragma unroll
      for (int k = 0; k < 8; ++k) {
        float4 h = *(const float4*)(bufB + (g * 8 + k) * 64 + c);
        acc[k] = fmaf(w[c], h.x, acc[k]);
        acc[k] = fmaf(w[c + 1], h.y, acc[k]);
        acc[k] = fmaf(w[c + 2], h.z, acc[k]);
        acc[k] = fmaf(w[c + 3], h.w, acc[k]);
      }
    }
#pragma unroll
    for (int k = 0; k < 8; ++k) bufA[(g * 8 + k) * 64 + o] = fmaxf(acc[k], 0.0f);
  }
  __syncthreads();
  // layer 3: 64->128 (thread = (o128, 16-sample group)), fused relu+max
  {
    const int o = tid & 127, g = tid >> 7;
    float w[64];
    const float* wr = W3 + o * 64;
#pragma unroll
    for (int c = 0; c < 64; ++c) w[c] = wr[c];
    float bias = b3[o];
    float acc[16];
#pragma unroll
    for (int k = 0; k < 16; ++k) acc[k] = bias;
#pragma unroll
    for (int kb = 0; kb < 16; kb += 8) {   // 8-sample sub-blocks to limit live registers
#pragma unroll
      for (int c = 0; c < 64; c += 4) {
#pragma unroll
        for (int k = 0; k < 8; ++k) {
          float4 h = *(const float4*)(bufA + (g * 16 + kb + k) * 64 + c);
          acc[kb + k] = fmaf(w[c], h.x, acc[kb + k]);
          acc[kb + k] = fmaf(w[c + 1], h.y, acc[kb + k]);
          acc[kb + k] = fmaf(w[c + 2], h.z, acc[kb + k]);
          acc[kb + k] = fmaf(w[c + 3], h.w, acc[kb + k]);
        }
      }
    }
    float mx = 0.0f;
#pragma unroll
    for (int k = 0; k < 16; ++k) mx = fmaxf(mx, fmaxf(acc[k], 0.0f));
    bufB[g * 128 + o] = mx;
  }
  __syncthreads();
  if (tid < 128) {
    float v = fmaxf(bufB[tid], bufB[128 + tid]);
    outf[((size_t)b * 128 + tid) * NPT + m] = v;
  }
}

extern "C" void kernel_launch(void* const* d_in, const int* in_sizes, int n_in,
                              void* d_out, int out_size, void* d_ws, size_t ws_size,
                              hipStream_t stream) {
  const float* xyz   = (const float*)d_in[0];
  const float* feats = (const float*)d_in[1];
  const float* W1 = (const float*)d_in[2];
  const float* b1 = (const float*)d_in[3];
  const float* W2 = (const float*)d_in[4];
  const float* b2 = (const float*)d_in[5];
  const float* W3 = (const float*)d_in[6];
  const float* b3 = (const float*)d_in[7];
  float* out = (float*)d_out;
  float* newxyz = out;                 // (4,1024,3)
  float* outf = out + NB * NPT * 3;    // (4,128,1024)
  int* ballidx = (int*)d_ws;           // 4096*32 ints

  hipLaunchKernelGGL(fps_kernel, dim3(NB), dim3(256), 0, stream, xyz, newxyz);
  hipLaunchKernelGGL(ball_kernel, dim3(NB * NPT / 4), dim3(256), 0, stream, xyz, newxyz, ballidx);
  hipLaunchKernelGGL(mlp_kernel, dim3(NB * NPT), dim3(256), 0, stream,
                     xyz, feats, newxyz, ballidx, W1, b1, W2, b2, W3, b3, outf);
}

// Round 6
// 2353.950 us; speedup vs baseline: 1.0233x; 1.0233x over previous
//
#include <hip/hip_runtime.h>

#define NB 4
#define NN 16384
#define NPT 1024
#define NS 32
#define CIN 64
#define C0 67

__device__ __forceinline__ unsigned long long shfl_xor_u64(unsigned long long v, int m) {
  int lo = __shfl_xor((int)(unsigned)v, m, 64);
  int hi = __shfl_xor((int)(unsigned)(v >> 32), m, 64);
  return ((unsigned long long)(unsigned)hi << 32) | (unsigned)lo;
}

// ---------------- FPS: one block per batch, 256 threads, 64 pts/thread in registers ----
// Rounds 4/5 lesson: px+py+pz+md = 256 + ~45 working = ~300 live values, but the
// allocator targeted ~3 waves/SIMD (~170 VGPR) and REMATERIALIZED the coord arrays by
// re-loading 192KB/CU from L2 every iteration (~3200 cyc, the real bottleneck).
// Fix: (1) amdgpu_waves_per_eu(1,1) pins the occupancy target to 1 wave/EU -> 512-reg
// unified VGPR+AGPR budget; (2) volatile initial loads make remat-by-reload illegal.
extern "C" __global__ __attribute__((amdgpu_waves_per_eu(1, 1))) __launch_bounds__(256)
void fps_kernel(const float* __restrict__ xyz, float* __restrict__ newxyz) {
  const int b = blockIdx.x;
  const int tid = threadIdx.x;          // 0..255
  const int wv = tid >> 6, lane = tid & 63;
  const float* base = xyz + (size_t)b * (NN * 3);
  const volatile float* vbase = base;   // volatile: loads cannot be duplicated/rematerialized
  float px[64], py[64], pz[64], md[64];
#pragma unroll
  for (int k = 0; k < 64; ++k) {
    int j = (k << 8) + tid;
    px[k] = vbase[3 * j + 0];
    py[k] = vbase[3 * j + 1];
    pz[k] = vbase[3 * j + 2];
    md[k] = 1e10f;
  }
  __shared__ unsigned long long part[2][4];  // parity-double-buffered wave-winner keys
  float* onew = newxyz + (size_t)b * (NPT * 3);
  // iteration 0: centroid = point 0 (broadcast load)
  float cx = base[0], cy = base[1], cz = base[2];
  if (tid == 0) { onew[0] = cx; onew[1] = cy; onew[2] = cz; }
  for (int it = 1; it < NPT; ++it) {
    const int p = it & 1;
    float bestv = -1.0f; int bestk = 0;
#pragma unroll
    for (int k = 0; k < 64; ++k) {
      // match numpy exactly: no FMA contraction, sum order (dx2+dy2)+dz2
      float dx = __fsub_rn(px[k], cx);
      float dy = __fsub_rn(py[k], cy);
      float dz = __fsub_rn(pz[k], cz);
      float d = __fadd_rn(__fadd_rn(__fmul_rn(dx, dx), __fmul_rn(dy, dy)), __fmul_rn(dz, dz));
      float mn = fminf(md[k], d);
      md[k] = mn;
      bool gt = mn > bestv;            // strict > keeps earliest k (lowest j in-thread)
      bestv = gt ? mn : bestv;
      bestk = gt ? k : bestk;          // bestk only feeds the integer j below (no array read)
    }
    int bestj = (bestk << 8) + tid;
    // d>=0 so float bits are monotonic; ~idx breaks ties toward the SMALLEST index
    unsigned long long key = ((unsigned long long)__float_as_uint(bestv) << 32) | (unsigned)(~bestj);
    unsigned long long red = key;
#pragma unroll
    for (int off = 32; off > 0; off >>= 1) {
      unsigned long long o = shfl_xor_u64(red, off);
      red = (o > red) ? o : red;
    }
    if (lane == 0) part[p][wv] = red;
    __syncthreads();
    // every thread combines the 4 wave winners locally (broadcast LDS reads)
    unsigned long long g0 = part[p][0], g1 = part[p][1], g2 = part[p][2], g3 = part[p][3];
    unsigned long long ga = (g0 > g1) ? g0 : g1;
    unsigned long long gb = (g2 > g3) ? g2 : g3;
    unsigned long long g = (ga > gb) ? ga : gb;
    int j = (int)(~(unsigned)g);
    int js = __builtin_amdgcn_readfirstlane(j);      // uniform -> scalar loads
    const float* pc = base + 3 * js;
    cx = pc[0]; cy = pc[1]; cz = pc[2];              // bit-identical to source coords
    if (tid == 0) { float* o3 = onew + 3 * it; o3[0] = cx; o3[1] = cy; o3[2] = cz; }
    // no second barrier: next iteration writes the OTHER parity's cells
  }
}

// ---------------- Ball query: one wave per centroid, ordered append with early exit ----------------
extern "C" __global__ __launch_bounds__(256)
void ball_kernel(const float* __restrict__ xyz, const float* __restrict__ newxyz,
                 int* __restrict__ ballidx) {
  const int lwv = threadIdx.x >> 6, lane = threadIdx.x & 63;
  const int wid = blockIdx.x * 4 + lwv;  // centroid id, 0..4095
  const int b = wid >> 10;
  const float* base = xyz + (size_t)b * (NN * 3);
  const float* c = newxyz + (size_t)wid * 3;
  float cx = c[0], cy = c[1], cz = c[2];
  float c2 = __fadd_rn(__fadd_rn(__fmul_rn(cx, cx), __fmul_rn(cy, cy)), __fmul_rn(cz, cz));
  __shared__ int list[4][NS];
  int cnt = 0;
  for (int j0 = 0; j0 < NN; j0 += 64) {
    int j = j0 + lane;
    float xx = base[3 * j + 0], xy = base[3 * j + 1], xz = base[3 * j + 2];
    float x2 = __fadd_rn(__fadd_rn(__fmul_rn(xx, xx), __fmul_rn(xy, xy)), __fmul_rn(xz, xz));
    float dt = __fadd_rn(__fadd_rn(__fmul_rn(cx, xx), __fmul_rn(cy, xy)), __fmul_rn(cz, xz));
    float d2 = __fsub_rn(__fadd_rn(c2, x2), __fmul_rn(2.0f, dt));  // (c2+x2) - 2*dot
    bool in = d2 < 0.25f;
    unsigned long long msk = __ballot(in);
    if (in) {
      int pos = cnt + (int)__popcll(msk & ((1ull << lane) - 1ull));
      if (pos < NS) list[lwv][pos] = j;
    }
    cnt += (int)__popcll(msk);
    if (cnt >= NS) break;
  }
  if (lane < NS) {
    int v;
    if (cnt == 0) v = 0;
    else v = (lane < cnt) ? list[lwv][lane] : list[lwv][0];
    ballidx[wid * NS + lane] = v;
  }
}

// ---------------- Gather + MLP(67->64->64->128) + max-pool, one block per (b,m) ----------------
extern "C" __global__ __launch_bounds__(256)
void mlp_kernel(const float* __restrict__ xyz, const float* __restrict__ feats,
                const float* __restrict__ newxyz, const int* __restrict__ ballidx,
                const float* __restrict__ W1, const float* __restrict__ b1,
                const float* __restrict__ W2, const float* __restrict__ b2,
                const float* __restrict__ W3, const float* __restrict__ b3,
                float* __restrict__ outf) {
  const int bm = blockIdx.x;
  const int b = bm >> 10, m = bm & 1023;
  const int tid = threadIdx.x;
  __align__(16) __shared__ float bufA[32 * 68];  // h0 (stride 68), then h2 (stride 64)
  __align__(16) __shared__ float bufB[32 * 64];  // h1, then partial max
  __shared__ int sidx[NS];
  if (tid < NS) sidx[tid] = ballidx[bm * NS + tid];
  const float* cb = newxyz + (size_t)bm * 3;
  float cx = cb[0], cy = cb[1], cz = cb[2];
  __syncthreads();
  // gather: 8 threads per sample
  {
    int s = tid >> 3, q = tid & 7;
    int j = sidx[s];
    float* row = bufA + s * 68;
    const float* fb = feats + (size_t)b * (CIN * NN) + j;
#pragma unroll
    for (int u = 0; u < 8; ++u) {
      int cc = (q << 3) + u;
      row[3 + cc] = fb[(size_t)cc * NN];
    }
    if (q == 0) {
      const float* p = xyz + ((size_t)b * NN + j) * 3;
      row[0] = __fsub_rn(p[0], cx);
      row[1] = __fsub_rn(p[1], cy);
      row[2] = __fsub_rn(p[2], cz);
      row[67] = 0.0f;
    }
  }
  __syncthreads();
  // layer 1: 67->64   (thread = (o, 8-sample group))
  {
    const int o = tid & 63, g = tid >> 6;
    float w[68];
    const float* wr = W1 + o * C0;
#pragma unroll
    for (int c = 0; c < C0; ++c) w[c] = wr[c];
    w[67] = 0.0f;
    float bias = b1[o];
    float acc[8];
#pragma unroll
    for (int k = 0; k < 8; ++k) acc[k] = bias;
#pragma unroll
    for (int c = 0; c < 68; c += 4) {
#pragma unroll
      for (int k = 0; k < 8; ++k) {
        float4 h = *(const float4*)(bufA + (g * 8 + k) * 68 + c);
        acc[k] = fmaf(w[c], h.x, acc[k]);
        acc[k] = fmaf(w[c + 1], h.y, acc[k]);
        acc[k] = fmaf(w[c + 2], h.z, acc[k]);
        acc[k] = fmaf(w[c + 3], h.w, acc[k]);
      }
    }
#pragma unroll
    for (int k = 0; k < 8; ++k) bufB[(g * 8 + k) * 64 + o] = fmaxf(acc[k], 0.0f);
  }
  __syncthreads();
  // layer 2: 64->64, h2 into bufA with stride 64
  {
    const int o = tid & 63, g = tid >> 6;
    float w[64];
    const float* wr = W2 + o * 64;
#pragma unroll
    for (int c = 0; c < 64; ++c) w[c] = wr[c];
    float bias = b2[o];
    float acc[8];
#pragma unroll
    for (int k = 0; k < 8; ++k) acc[k] = bias;
#pragma unroll
    for (int c = 0; c < 64; c += 4) {
#pragma unroll
      for (int k = 0; k < 8; ++k) {
        float4 h = *(const float4*)(bufB + (g * 8 + k) * 64 + c);
        acc[k] = fmaf(w[c], h.x, acc[k]);
        acc[k] = fmaf(w[c + 1], h.y, acc[k]);
        acc[k] = fmaf(w[c + 2], h.z, acc[k]);
        acc[k] = fmaf(w[c + 3], h.w, acc[k]);
      }
    }
#pragma unroll
    for (int k = 0; k < 8; ++k) bufA[(g * 8 + k) * 64 + o] = fmaxf(acc[k], 0.0f);
  }
  __syncthreads();
  // layer 3: 64->128 (thread = (o128, 16-sample group)), fused relu+max
  {
    const int o = tid & 127, g = tid >> 7;
    float w[64];
    const float* wr = W3 + o * 64;
#pragma unroll
    for (int c = 0; c < 64; ++c) w[c] = wr[c];
    float bias = b3[o];
    float acc[16];
#pragma unroll
    for (int k = 0; k < 16; ++k) acc[k] = bias;
#pragma unroll
    for (int kb = 0; kb < 16; kb += 8) {   // 8-sample sub-blocks to limit live registers
#pragma unroll
      for (int c = 0; c < 64; c += 4) {
#pragma unroll
        for (int k = 0; k < 8; ++k) {
          float4 h = *(const float4*)(bufA + (g * 16 + kb + k) * 64 + c);
          acc[kb + k] = fmaf(w[c], h.x, acc[kb + k]);
          acc[kb + k] = fmaf(w[c + 1], h.y, acc[kb + k]);
          acc[kb + k] = fmaf(w[c + 2], h.z, acc[kb + k]);
          acc[kb + k] = fmaf(w[c + 3], h.w, acc[kb + k]);
        }
      }
    }
    float mx = 0.0f;
#pragma unroll
    for (int k = 0; k < 16; ++k) mx = fmaxf(mx, fmaxf(acc[k], 0.0f));
    bufB[g * 128 + o] = mx;
  }
  __syncthreads();
  if (tid < 128) {
    float v = fmaxf(bufB[tid], bufB[128 + tid]);
    outf[((size_t)b * 128 + tid) * NPT + m] = v;
  }
}

extern "C" void kernel_launch(void* const* d_in, const int* in_sizes, int n_in,
                              void* d_out, int out_size, void* d_ws, size_t ws_size,
                              hipStream_t stream) {
  const float* xyz   = (const float*)d_in[0];
  const float* feats = (const float*)d_in[1];
  const float* W1 = (const float*)d_in[2];
  const float* b1 = (const float*)d_in[3];
  const float* W2 = (const float*)d_in[4];
  const float* b2 = (const float*)d_in[5];
  const float* W3 = (const float*)d_in[6];
  const float* b3 = (const float*)d_in[7];
  float* out = (float*)d_out;
  float* newxyz = out;                 // (4,1024,3)
  float* outf = out + NB * NPT * 3;    // (4,128,1024)
  int* ballidx = (int*)d_ws;           // 4096*32 ints

  hipLaunchKernelGGL(fps_kernel, dim3(NB), dim3(256), 0, stream, xyz, newxyz);
  hipLaunchKernelGGL(ball_kernel, dim3(NB * NPT / 4), dim3(256), 0, stream, xyz, newxyz, ballidx);
  hipLaunchKernelGGL(mlp_kernel, dim3(NB * NPT), dim3(256), 0, stream,
                     xyz, feats, newxyz, ballidx, W1, b1, W2, b2, W3, b3, outf);
}

// Round 7
// 1973.704 us; speedup vs baseline: 1.2204x; 1.1927x over previous
//
#include <hip/hip_runtime.h>

#define NB 4
#define NN 16384
#define NPT 1024
#define NS 32
#define CIN 64
#define C0 67

__device__ __forceinline__ unsigned long long shfl_xor_u64(unsigned long long v, int m) {
  int lo = __shfl_xor((int)(unsigned)v, m, 64);
  int hi = __shfl_xor((int)(unsigned)(v >> 32), m, 64);
  return ((unsigned long long)(unsigned)hi << 32) | (unsigned)lo;
}

// ---------------- FPS: one block per batch, 512 threads, 32 pts/thread ----------------
// Rounds 3-6 lesson: a 256-thread layout needs ~300 live regs/thread > the 256
// architected-VGPR cap -> the allocator MUST spill/remat (L2 scratch round-trips every
// iteration, ~1.2us/iter, invisible in HBM counters). Fix the layout, not the allocator:
// 512 threads x 32 pts/thread = 128 data regs + ~35 working < 256 budget at
// waves_per_eu(2,2) (exactly 2 waves/EU -> 256-VGPR allocation target).
extern "C" __global__ __attribute__((amdgpu_waves_per_eu(2, 2))) __launch_bounds__(512)
void fps_kernel(const float* __restrict__ xyz, float* __restrict__ newxyz) {
  const int b = blockIdx.x;
  const int tid = threadIdx.x;          // 0..511
  const int wv = tid >> 6, lane = tid & 63;
  const float* base = xyz + (size_t)b * (NN * 3);
  float px[32], py[32], pz[32], md[32];
#pragma unroll
  for (int k = 0; k < 32; ++k) {
    int j = (k << 9) + tid;
    px[k] = base[3 * j + 0];
    py[k] = base[3 * j + 1];
    pz[k] = base[3 * j + 2];
    md[k] = 1e10f;
  }
  __shared__ unsigned long long part[2][8];  // parity-double-buffered wave-winner keys
  float* onew = newxyz + (size_t)b * (NPT * 3);
  // iteration 0: centroid = point 0 (broadcast load)
  float cx = base[0], cy = base[1], cz = base[2];
  if (tid == 0) { onew[0] = cx; onew[1] = cy; onew[2] = cz; }
  for (int it = 1; it < NPT; ++it) {
    const int p = it & 1;
    float bestv = -1.0f; int bestk = 0;
#pragma unroll
    for (int k = 0; k < 32; ++k) {
      // match numpy exactly: no FMA contraction, sum order (dx2+dy2)+dz2
      float dx = __fsub_rn(px[k], cx);
      float dy = __fsub_rn(py[k], cy);
      float dz = __fsub_rn(pz[k], cz);
      float d = __fadd_rn(__fadd_rn(__fmul_rn(dx, dx), __fmul_rn(dy, dy)), __fmul_rn(dz, dz));
      float mn = fminf(md[k], d);
      md[k] = mn;
      bool gt = mn > bestv;            // strict > keeps earliest k (lowest j in-thread)
      bestv = gt ? mn : bestv;
      bestk = gt ? k : bestk;          // bestk only feeds the integer j below (no array read)
    }
    int bestj = (bestk << 9) + tid;
    // d>=0 so float bits are monotonic; ~idx breaks ties toward the SMALLEST index
    unsigned long long key = ((unsigned long long)__float_as_uint(bestv) << 32) | (unsigned)(~bestj);
    unsigned long long red = key;
#pragma unroll
    for (int off = 32; off > 0; off >>= 1) {
      unsigned long long o = shfl_xor_u64(red, off);
      red = (o > red) ? o : red;
    }
    if (lane == 0) part[p][wv] = red;
    __syncthreads();
    // every thread combines the 8 wave winners locally (broadcast LDS reads)
    unsigned long long g = part[p][0];
#pragma unroll
    for (int w = 1; w < 8; ++w) {
      unsigned long long o = part[p][w];
      g = (o > g) ? o : g;
    }
    int j = (int)(~(unsigned)g);
    int js = __builtin_amdgcn_readfirstlane(j);      // uniform -> scalar loads
    const float* pc = base + 3 * js;
    cx = pc[0]; cy = pc[1]; cz = pc[2];              // bit-identical to source coords
    if (tid == 0) { float* o3 = onew + 3 * it; o3[0] = cx; o3[1] = cy; o3[2] = cz; }
    // no second barrier: next iteration writes the OTHER parity's cells
  }
}

// ---------------- Ball query: one wave per centroid, ordered append with early exit ----------------
extern "C" __global__ __launch_bounds__(256)
void ball_kernel(const float* __restrict__ xyz, const float* __restrict__ newxyz,
                 int* __restrict__ ballidx) {
  const int lwv = threadIdx.x >> 6, lane = threadIdx.x & 63;
  const int wid = blockIdx.x * 4 + lwv;  // centroid id, 0..4095
  const int b = wid >> 10;
  const float* base = xyz + (size_t)b * (NN * 3);
  const float* c = newxyz + (size_t)wid * 3;
  float cx = c[0], cy = c[1], cz = c[2];
  float c2 = __fadd_rn(__fadd_rn(__fmul_rn(cx, cx), __fmul_rn(cy, cy)), __fmul_rn(cz, cz));
  __shared__ int list[4][NS];
  int cnt = 0;
  for (int j0 = 0; j0 < NN; j0 += 64) {
    int j = j0 + lane;
    float xx = base[3 * j + 0], xy = base[3 * j + 1], xz = base[3 * j + 2];
    float x2 = __fadd_rn(__fadd_rn(__fmul_rn(xx, xx), __fmul_rn(xy, xy)), __fmul_rn(xz, xz));
    float dt = __fadd_rn(__fadd_rn(__fmul_rn(cx, xx), __fmul_rn(cy, xy)), __fmul_rn(cz, xz));
    float d2 = __fsub_rn(__fadd_rn(c2, x2), __fmul_rn(2.0f, dt));  // (c2+x2) - 2*dot
    bool in = d2 < 0.25f;
    unsigned long long msk = __ballot(in);
    if (in) {
      int pos = cnt + (int)__popcll(msk & ((1ull << lane) - 1ull));
      if (pos < NS) list[lwv][pos] = j;
    }
    cnt += (int)__popcll(msk);
    if (cnt >= NS) break;
  }
  if (lane < NS) {
    int v;
    if (cnt == 0) v = 0;
    else v = (lane < cnt) ? list[lwv][lane] : list[lwv][0];
    ballidx[wid * NS + lane] = v;
  }
}

// ---------------- Gather + MLP(67->64->64->128) + max-pool, one block per (b,m) ----------------
extern "C" __global__ __launch_bounds__(256)
void mlp_kernel(const float* __restrict__ xyz, const float* __restrict__ feats,
                const float* __restrict__ newxyz, const int* __restrict__ ballidx,
                const float* __restrict__ W1, const float* __restrict__ b1,
                const float* __restrict__ W2, const float* __restrict__ b2,
                const float* __restrict__ W3, const float* __restrict__ b3,
                float* __restrict__ outf) {
  const int bm = blockIdx.x;
  const int b = bm >> 10, m = bm & 1023;
  const int tid = threadIdx.x;
  __align__(16) __shared__ float bufA[32 * 68];  // h0 (stride 68), then h2 (stride 64)
  __align__(16) __shared__ float bufB[32 * 64];  // h1, then partial max
  __shared__ int sidx[NS];
  if (tid < NS) sidx[tid] = ballidx[bm * NS + tid];
  const float* cb = newxyz + (size_t)bm * 3;
  float cx = cb[0], cy = cb[1], cz = cb[2];
  __syncthreads();
  // gather: 8 threads per sample
  {
    int s = tid >> 3, q = tid & 7;
    int j = sidx[s];
    float* row = bufA + s * 68;
    const float* fb = feats + (size_t)b * (CIN * NN) + j;
#pragma unroll
    for (int u = 0; u < 8; ++u) {
      int cc = (q << 3) + u;
      row[3 + cc] = fb[(size_t)cc * NN];
    }
    if (q == 0) {
      const float* p = xyz + ((size_t)b * NN + j) * 3;
      row[0] = __fsub_rn(p[0], cx);
      row[1] = __fsub_rn(p[1], cy);
      row[2] = __fsub_rn(p[2], cz);
      row[67] = 0.0f;
    }
  }
  __syncthreads();
  // layer 1: 67->64   (thread = (o, 8-sample group))
  {
    const int o = tid & 63, g = tid >> 6;
    float w[68];
    const float* wr = W1 + o * C0;
#pragma unroll
    for (int c = 0; c < C0; ++c) w[c] = wr[c];
    w[67] = 0.0f;
    float bias = b1[o];
    float acc[8];
#pragma unroll
    for (int k = 0; k < 8; ++k) acc[k] = bias;
#pragma unroll
    for (int c = 0; c < 68; c += 4) {
#pragma unroll
      for (int k = 0; k < 8; ++k) {
        float4 h = *(const float4*)(bufA + (g * 8 + k) * 68 + c);
        acc[k] = fmaf(w[c], h.x, acc[k]);
        acc[k] = fmaf(w[c + 1], h.y, acc[k]);
        acc[k] = fmaf(w[c + 2], h.z, acc[k]);
        acc[k] = fmaf(w[c + 3], h.w, acc[k]);
      }
    }
#pragma unroll
    for (int k = 0; k < 8; ++k) bufB[(g * 8 + k) * 64 + o] = fmaxf(acc[k], 0.0f);
  }
  __syncthreads();
  // layer 2: 64->64, h2 into bufA with stride 64
  {
    const int o = tid & 63, g = tid >> 6;
    float w[64];
    const float* wr = W2 + o * 64;
#pragma unroll
    for (int c = 0; c < 64; ++c) w[c] = wr[c];
    float bias = b2[o];
    float acc[8];
#pragma unroll
    for (int k = 0; k < 8; ++k) acc[k] = bias;
#pragma unroll
    for (int c = 0; c < 64; c += 4) {
#pragma unroll
      for (int k = 0; k < 8; ++k) {
        float4 h = *(const float4*)(bufB + (g * 8 + k) * 64 + c);
        acc[k] = fmaf(w[c], h.x, acc[k]);
        acc[k] = fmaf(w[c + 1], h.y, acc[k]);
        acc[k] = fmaf(w[c + 2], h.z, acc[k]);
        acc[k] = fmaf(w[c + 3], h.w, acc[k]);
      }
    }
#pragma unroll
    for (int k = 0; k < 8; ++k) bufA[(g * 8 + k) * 64 + o] = fmaxf(acc[k], 0.0f);
  }
  __syncthreads();
  // layer 3: 64->128 (thread = (o128, 16-sample group)), fused relu+max
  {
    const int o = tid & 127, g = tid >> 7;
    float w[64];
    const float* wr = W3 + o * 64;
#pragma unroll
    for (int c = 0; c < 64; ++c) w[c] = wr[c];
    float bias = b3[o];
    float acc[16];
#pragma unroll
    for (int k = 0; k < 16; ++k) acc[k] = bias;
#pragma unroll
    for (int kb = 0; kb < 16; kb += 8) {   // 8-sample sub-blocks to limit live registers
#pragma unroll
      for (int c = 0; c < 64; c += 4) {
#pragma unroll
        for (int k = 0; k < 8; ++k) {
          float4 h = *(const float4*)(bufA + (g * 16 + kb + k) * 64 + c);
          acc[kb + k] = fmaf(w[c], h.x, acc[kb + k]);
          acc[kb + k] = fmaf(w[c + 1], h.y, acc[kb + k]);
          acc[kb + k] = fmaf(w[c + 2], h.z, acc[kb + k]);
          acc[kb + k] = fmaf(w[c + 3], h.w, acc[kb + k]);
        }
      }
    }
    float mx = 0.0f;
#pragma unroll
    for (int k = 0; k < 16; ++k) mx = fmaxf(mx, fmaxf(acc[k], 0.0f));
    bufB[g * 128 + o] = mx;
  }
  __syncthreads();
  if (tid < 128) {
    float v = fmaxf(bufB[tid], bufB[128 + tid]);
    outf[((size_t)b * 128 + tid) * NPT + m] = v;
  }
}

extern "C" void kernel_launch(void* const* d_in, const int* in_sizes, int n_in,
                              void* d_out, int out_size, void* d_ws, size_t ws_size,
                              hipStream_t stream) {
  const float* xyz   = (const float*)d_in[0];
  const float* feats = (const float*)d_in[1];
  const float* W1 = (const float*)d_in[2];
  const float* b1 = (const float*)d_in[3];
  const float* W2 = (const float*)d_in[4];
  const float* b2 = (const float*)d_in[5];
  const float* W3 = (const float*)d_in[6];
  const float* b3 = (const float*)d_in[7];
  float* out = (float*)d_out;
  float* newxyz = out;                 // (4,1024,3)
  float* outf = out + NB * NPT * 3;    // (4,128,1024)
  int* ballidx = (int*)d_ws;           // 4096*32 ints

  hipLaunchKernelGGL(fps_kernel, dim3(NB), dim3(512), 0, stream, xyz, newxyz);
  hipLaunchKernelGGL(ball_kernel, dim3(NB * NPT / 4), dim3(256), 0, stream, xyz, newxyz, ballidx);
  hipLaunchKernelGGL(mlp_kernel, dim3(NB * NPT), dim3(256), 0, stream,
                     xyz, feats, newxyz, ballidx, W1, b1, W2, b2, W3, b3, outf);
}